// Round 2
// 176.362 us; speedup vs baseline: 1.1024x; 1.1024x over previous
//
#include <hip/hip_runtime.h>
#include <math.h>

#define GAMMA_F 1.4f
#define EPS_F 1e-6f
#define B_ 16
#define K_ 64
#define NT_ 128
#define NX_ 256
#define NI 63            // K-1 interfaces
#define N_NEWTON 20

// bias_kernel geometry
#define PTS_PER_ITER 16
#define ITERS 8
#define PTS_PER_BLOCK (PTS_PER_ITER * ITERS)          // 128
#define BLOCKS_PER_B (NT_ * NX_ / PTS_PER_BLOCK)      // 256

// native vector type for nontemporal stores (HIP float4 is a class and
// __builtin_nontemporal_store rejects it)
typedef float floatx4 __attribute__((ext_vector_type(4)));

// ---------------------------------------------------------------------------
// wave_f_df exactly as reference (clip(x, EPS) == max(x, EPS)).
// One powf instead of two: p_ratio^(-(g+1)/(2g)) == p_ratio^(exp_rare-1)
//                                                == p_ratio^exp_rare / p_ratio
// ---------------------------------------------------------------------------
__device__ __forceinline__ void wave_f_df(float p, float p_K, float A_K, float B_K,
                                          float c_K, float& f, float& df) {
    const float gm1 = GAMMA_F - 1.0f;
    const float exp_rare = gm1 / (2.0f * GAMMA_F);
    float denom = fmaxf(p + B_K, EPS_F);
    float sqrt_AoD = sqrtf(fmaxf(A_K / denom, EPS_F));
    float f_shock = (p - p_K) * sqrt_AoD;
    float df_shock = sqrt_AoD * (1.0f - (p - p_K) / (2.0f * denom));
    float pKc = fmaxf(p_K, EPS_F);
    float p_ratio = fmaxf(p / pKc, EPS_F);
    float pre = powf(p_ratio, exp_rare);                       // single powf
    float f_rare = 2.0f * c_K / gm1 * (pre - 1.0f);
    float df_rare = c_K / (GAMMA_F * pKc) * (pre / p_ratio);   // ^(exp_rare-1)
    bool is_shock = p > p_K;
    f = is_shock ? f_shock : f_rare;
    df = is_shock ? df_shock : df_rare;
}

// ---------------------------------------------------------------------------
// Kernel A: one thread per (batch, interface). 16 blocks x 64 threads.
// ---------------------------------------------------------------------------
__global__ void riemann_solve_kernel(const float* __restrict__ xs,
                                     const float* __restrict__ ks,
                                     const float* __restrict__ ks_v,
                                     const float* __restrict__ ks_p,
                                     float* __restrict__ sr_ws,
                                     float* __restrict__ sl_ws,
                                     float* __restrict__ xd_ws) {
    const int b = blockIdx.x;
    const int i = threadIdx.x;
    if (i >= NI) return;

    const float gm1 = GAMMA_F - 1.0f;
    const float gp1 = GAMMA_F + 1.0f;
    const float exp_rare = gm1 / (2.0f * GAMMA_F);

    const int base = b * K_ + i;
    float rho_L = ks[base],     rho_R = ks[base + 1];
    float u_L   = ks_v[base],   u_R   = ks_v[base + 1];
    float p_L   = ks_p[base],   p_R   = ks_p[base + 1];
    const float du = u_R - u_L;

    float c_L = sqrtf(fmaxf(GAMMA_F * p_L / fmaxf(rho_L, EPS_F), EPS_F));
    float c_R = sqrtf(fmaxf(GAMMA_F * p_R / fmaxf(rho_R, EPS_F), EPS_F));
    float A_L = 2.0f / (gp1 * fmaxf(rho_L, EPS_F));
    float A_R = 2.0f / (gp1 * fmaxf(rho_R, EPS_F));
    float B_L = gm1 / gp1 * p_L;
    float B_R = gm1 / gp1 * p_R;

    // initial guess (two-rarefaction)
    float num = c_L + c_R - 0.5f * gm1 * du;
    float den = c_L / powf(fmaxf(p_L, EPS_F), exp_rare)
              + c_R / powf(fmaxf(p_R, EPS_F), exp_rare);
    float p_star = fmaxf(powf(num / den, 1.0f / exp_rare), EPS_F);

    #pragma unroll 1
    for (int it = 0; it < N_NEWTON; ++it) {
        float fL, dfL, fR, dfR;
        wave_f_df(p_star, p_L, A_L, B_L, c_L, fL, dfL);
        wave_f_df(p_star, p_R, A_R, B_R, c_R, fR, dfR);
        float residual = fL + fR + du;
        float jac = fmaxf(dfL + dfR, EPS_F);
        p_star = fmaxf(p_star - residual / jac, EPS_F);
    }

    const float gp1_o_2g = gp1 / (2.0f * GAMMA_F);
    float s1 = u_L - c_L * sqrtf(fmaxf(1.0f + gp1_o_2g * (p_star / fmaxf(p_L, EPS_F) - 1.0f), EPS_F));
    float speed_left = (p_star > p_L) ? s1 : (u_L - c_L);
    float s3 = u_R + c_R * sqrtf(fmaxf(1.0f + gp1_o_2g * (p_star / fmaxf(p_R, EPS_F) - 1.0f), EPS_F));
    float speed_right = (p_star > p_R) ? s3 : (u_R + c_R);

    sl_ws[base] = speed_left;
    sr_ws[base] = speed_right;
    xd_ws[base] = xs[b * (K_ + 1) + i + 1];   // xs[:, 1:K]
}

// ---------------------------------------------------------------------------
// Kernel B: bias field. 256 threads/block; 16 lanes per point, 4 k's per lane.
// Each block covers 128 consecutive points (8 unrolled iterations), so the
// per-batch tables are staged into LDS once and hoisted into registers once.
// grid = B * 256 = 4096 blocks.
// ---------------------------------------------------------------------------
__global__ __launch_bounds__(256) void
bias_kernel(const float* __restrict__ t_coords,
            const float* __restrict__ x_coords,
            const float* __restrict__ pieces_mask,
            const float* __restrict__ sr_ws,
            const float* __restrict__ sl_ws,
            const float* __restrict__ xd_ws,
            float* __restrict__ out) {
    __shared__ float s_sr[NI];
    __shared__ float s_sl[NI];
    __shared__ float s_xd[NI];
    __shared__ float s_mask[K_];

    const int bid = blockIdx.x;
    const int b = bid >> 8;             // / BLOCKS_PER_B (256)
    const int blk_in_b = bid & 255;
    const int tid = threadIdx.x;

    // stage per-batch tables into LDS (once per 128 points)
    {
        const int g = tid >> 6;         // 0..3
        const int r = tid & 63;
        if (g == 0) { if (r < NI) s_sr[r] = sr_ws[b * K_ + r]; }
        else if (g == 1) { if (r < NI) s_sl[r] = sl_ws[b * K_ + r]; }
        else if (g == 2) { if (r < NI) s_xd[r] = xd_ws[b * K_ + r]; }
        else { s_mask[r] = pieces_mask[b * K_ + r]; }
    }
    __syncthreads();

    const int p_local = tid >> 4;       // 0..15, point within chunk
    const int j = tid & 15;             // k-quad index
    const int k0 = j << 2;

    // ---- hoist loop-invariant per-k tables into registers -----------------
    // xi needed at k = k0-1 .. k0+3  (5 values); sentinels make the padded
    // entries contribute exactly 0 through the relu:
    //   k == NI (63): sr = +3e38  -> relu(xi - 3e38) = 0   (pad_last)
    //   k == 0      : sl = -3e38  -> relu(-3e38 - xi) = 0  (pad_first)
    float xdr[5];
    #pragma unroll
    for (int q = -1; q <= 3; ++q) {
        int k = k0 + q;
        xdr[q + 1] = (k >= 0 && k < NI) ? s_xd[k] : 0.0f;
    }
    float srr[4], slr[4], mkr[4], madd[4];
    #pragma unroll
    for (int q = 0; q < 4; ++q) {
        int k = k0 + q;
        srr[q] = (k < NI) ? s_sr[k] : 3.0e38f;
        slr[q] = (k >= 1) ? s_sl[k - 1] : -3.0e38f;
        float m = s_mask[k];
        mkr[q] = m;
        madd[q] = (m == 0.0f) ? -1.0e9f : 0.0f;
    }

    // ---- main loop: 8 chunks of 16 points ---------------------------------
    const int pt0 = blk_in_b * PTS_PER_BLOCK + p_local;
    const long long bbase = (long long)b * (NT_ * NX_);
    const float* tp = t_coords + bbase + pt0;
    const float* xp = x_coords + bbase + pt0;
    float* op = out + (bbase + pt0) * (long long)K_ + k0;

    #pragma unroll
    for (int it = 0; it < ITERS; ++it) {
        const float t = tp[it * PTS_PER_ITER];
        const float x = xp[it * PTS_PER_ITER];
        const float inv_t = 1.0f / (t + EPS_F);

        float xi[5];
        #pragma unroll
        for (int q = 0; q < 5; ++q)
            xi[q] = (x - xdr[q]) * inv_t;

        float r0, r1, r2, r3;
        {
            float pl, pr;
            pl = fmaxf(xi[1] - srr[0], 0.0f);
            pr = fmaxf(slr[0] - xi[0], 0.0f);
            r0 = -(pl + pr) * mkr[0] + madd[0];
            pl = fmaxf(xi[2] - srr[1], 0.0f);
            pr = fmaxf(slr[1] - xi[1], 0.0f);
            r1 = -(pl + pr) * mkr[1] + madd[1];
            pl = fmaxf(xi[3] - srr[2], 0.0f);
            pr = fmaxf(slr[2] - xi[2], 0.0f);
            r2 = -(pl + pr) * mkr[2] + madd[2];
            pl = fmaxf(xi[4] - srr[3], 0.0f);
            pr = fmaxf(slr[3] - xi[3], 0.0f);
            r3 = -(pl + pr) * mkr[3] + madd[3];
        }

        floatx4 v;
        v.x = r0; v.y = r1; v.z = r2; v.w = r3;
        __builtin_nontemporal_store(v, reinterpret_cast<floatx4*>(op));
        op += PTS_PER_ITER * K_;
    }
}

// ---------------------------------------------------------------------------
extern "C" void kernel_launch(void* const* d_in, const int* in_sizes, int n_in,
                              void* d_out, int out_size, void* d_ws, size_t ws_size,
                              hipStream_t stream) {
    const float* xs          = (const float*)d_in[0];
    const float* ks          = (const float*)d_in[1];
    const float* ks_v        = (const float*)d_in[2];
    const float* ks_p        = (const float*)d_in[3];
    const float* pieces_mask = (const float*)d_in[4];
    const float* t_coords    = (const float*)d_in[5];
    const float* x_coords    = (const float*)d_in[6];
    float* out = (float*)d_out;

    float* ws = (float*)d_ws;
    float* sr_ws = ws;                  // B*K floats
    float* sl_ws = ws + B_ * K_;        // B*K floats
    float* xd_ws = ws + 2 * B_ * K_;    // B*K floats

    riemann_solve_kernel<<<B_, 64, 0, stream>>>(xs, ks, ks_v, ks_p, sr_ws, sl_ws, xd_ws);

    const int blocks = B_ * BLOCKS_PER_B;   // 4096
    bias_kernel<<<blocks, 256, 0, stream>>>(t_coords, x_coords, pieces_mask,
                                            sr_ws, sl_ws, xd_ws, out);
}